// Round 1
// baseline (337.432 us; speedup 1.0000x reference)
//
#include <hip/hip_runtime.h>
#include <math.h>

typedef __bf16 bf16x8 __attribute__((ext_vector_type(8)));
typedef float f32x4 __attribute__((ext_vector_type(4)));
typedef unsigned short u16;

#define NQ 8192
#define DMODEL 512
#define NHEAD 8
#define DH 64
#define NC 2048
#define NIDX 100000

__device__ __forceinline__ u16 f2bf(float f) {
    unsigned u = __float_as_uint(f);
    u += 0x7fffu + ((u >> 16) & 1u);
    return (u16)(u >> 16);
}
__device__ __forceinline__ float bf2f(u16 h) {
    return __uint_as_float(((unsigned)h) << 16);
}

// ---------------- elementwise f32 -> bf16 ----------------
__global__ void k_cvt_bf16(const float* __restrict__ in, u16* __restrict__ out, int n) {
    int i = (blockIdx.x * 256 + threadIdx.x) * 4;
    if (i < n) {
        float4 v = *(const float4*)(in + i);
        ushort4 o;
        o.x = f2bf(v.x); o.y = f2bf(v.y); o.z = f2bf(v.z); o.w = f2bf(v.w);
        *(ushort4*)(out + i) = o;
    }
}

// ---------------- transpose (f32 or bf16 in) -> bf16 out[c][r] = in[r][c] ----------------
template <int IN_F32>
__global__ void k_transpose_bf16(const void* __restrict__ in_, u16* __restrict__ out, int R, int C) {
    __shared__ float tile[32][33];
    int c0 = blockIdx.x * 32, r0 = blockIdx.y * 32;
    int tx = threadIdx.x, ty = threadIdx.y;  // (32,8)
#pragma unroll
    for (int i = 0; i < 4; i++) {
        int r = r0 + ty + i * 8;
        float v;
        if (IN_F32) v = ((const float*)in_)[(size_t)r * C + c0 + tx];
        else        v = bf2f(((const u16*)in_)[(size_t)r * C + c0 + tx]);
        tile[ty + i * 8][tx] = v;
    }
    __syncthreads();
#pragma unroll
    for (int i = 0; i < 4; i++) {
        out[(size_t)(c0 + ty + i * 8) * R + r0 + tx] = f2bf(tile[tx][ty + i * 8]);
    }
}

// ---------------- histogram + log bias ----------------
__global__ void k_hist(const int* __restrict__ idx, int* __restrict__ counts, int n) {
    for (int i = blockIdx.x * blockDim.x + threadIdx.x; i < n; i += gridDim.x * blockDim.x)
        atomicAdd(&counts[idx[i]], 1);
}
__global__ void k_logbias(const int* __restrict__ counts, float* __restrict__ bias, int n) {
    int i = blockIdx.x * blockDim.x + threadIdx.x;
    if (i < n) bias[i] = logf((float)counts[i]);   // count==0 -> -inf (masks centroid)
}

// ---------------- bf16 GEMM: C[M][N] = A[M][K] * Bt[N][K]^T + bias[N] ----------------
__global__ __launch_bounds__(256) void k_gemm_bt(
    const u16* __restrict__ A, const u16* __restrict__ Bt,
    const float* __restrict__ bias, u16* __restrict__ Cmat,
    int M, int N, int K)
{
    constexpr int LDP = 40;  // padded row pitch (bf16 elems): 80B -> 2-way bank alias only
    __shared__ __align__(16) u16 As[128 * LDP];
    __shared__ __align__(16) u16 Bs[128 * LDP];
    int tid = threadIdx.x;
    int lane = tid & 63, wid = tid >> 6;
    int wrow = (wid >> 1) * 64, wcol = (wid & 1) * 64;
    int m0 = blockIdx.y * 128, n0 = blockIdx.x * 128;
    int lr = lane & 15, lg = lane >> 4;
    f32x4 acc[4][4] = {};

    for (int k0 = 0; k0 < K; k0 += 32) {
#pragma unroll
        for (int c = 0; c < 2; c++) {
            int ch = tid + c * 256;            // 512 chunks of 8 bf16
            int row = ch >> 2, colc = (ch & 3) * 8;
            uint4 av = *(const uint4*)(A + (size_t)(m0 + row) * K + k0 + colc);
            *(uint4*)(&As[row * LDP + colc]) = av;
            uint4 bv = *(const uint4*)(Bt + (size_t)(n0 + row) * K + k0 + colc);
            *(uint4*)(&Bs[row * LDP + colc]) = bv;
        }
        __syncthreads();
        bf16x8 af[4], bfr[4];
#pragma unroll
        for (int m = 0; m < 4; m++)
            af[m] = *(const bf16x8*)(&As[(wrow + m * 16 + lr) * LDP + lg * 8]);
#pragma unroll
        for (int n = 0; n < 4; n++)
            bfr[n] = *(const bf16x8*)(&Bs[(wcol + n * 16 + lr) * LDP + lg * 8]);
#pragma unroll
        for (int m = 0; m < 4; m++)
#pragma unroll
            for (int n = 0; n < 4; n++)
                acc[m][n] = __builtin_amdgcn_mfma_f32_16x16x32_bf16(af[m], bfr[n], acc[m][n], 0, 0, 0);
        __syncthreads();
    }
#pragma unroll
    for (int n = 0; n < 4; n++) {
        int col = n0 + wcol + n * 16 + lr;
        float bv = bias[col];
#pragma unroll
        for (int m = 0; m < 4; m++) {
            int rbase = m0 + wrow + m * 16 + lg * 4;
#pragma unroll
            for (int r = 0; r < 4; r++)
                Cmat[(size_t)(rbase + r) * N + col] = f2bf(acc[m][n][r] + bv);
        }
    }
}

// ---------------- flash attention over centroids ----------------
// grid (NQ/64, NHEAD), 4 waves; wave owns 16 q-rows of one head.
__global__ __launch_bounds__(256) void k_attn(
    const u16* __restrict__ Q, const u16* __restrict__ Km, const u16* __restrict__ Vt,
    const float* __restrict__ bias, float* __restrict__ Out, float scale)
{
    __shared__ float sbias[NC];
    __shared__ __align__(16) u16 sP[4 * 1024];  // per-wave 16x64 bf16 P tile (swizzled)
    int tid = threadIdx.x;
    for (int i = tid; i < NC; i += 256) sbias[i] = bias[i];
    __syncthreads();
    int lane = tid & 63, wid = tid >> 6;
    int lr = lane & 15, lg = lane >> 4;
    int h = blockIdx.y;
    int q0 = blockIdx.x * 64 + wid * 16;
    u16* P = sP + wid * 1024;

    bf16x8 aq[2];
#pragma unroll
    for (int kk = 0; kk < 2; kk++)
        aq[kk] = *(const bf16x8*)(Q + (size_t)(q0 + lr) * DMODEL + h * DH + kk * 32 + lg * 8);

    f32x4 o[4] = {};
    float m_run[4], l_run[4];
#pragma unroll
    for (int r = 0; r < 4; r++) { m_run[r] = -1e30f; l_run[r] = 0.f; }

    for (int c0 = 0; c0 < NC; c0 += 64) {
        f32x4 s[4];
#pragma unroll
        for (int ct = 0; ct < 4; ct++) {
            f32x4 a = {};
#pragma unroll
            for (int kk = 0; kk < 2; kk++) {
                bf16x8 bk = *(const bf16x8*)(Km + (size_t)(c0 + ct * 16 + lr) * DMODEL + h * DH + kk * 32 + lg * 8);
                a = __builtin_amdgcn_mfma_f32_16x16x32_bf16(aq[kk], bk, a, 0, 0, 0);
            }
            float bc = sbias[c0 + ct * 16 + lr];
#pragma unroll
            for (int r = 0; r < 4; r++) s[ct][r] = a[r] * scale + bc;
        }
#pragma unroll
        for (int r = 0; r < 4; r++) {
            float mx = fmaxf(fmaxf(s[0][r], s[1][r]), fmaxf(s[2][r], s[3][r]));
            mx = fmaxf(mx, __shfl_xor(mx, 1));
            mx = fmaxf(mx, __shfl_xor(mx, 2));
            mx = fmaxf(mx, __shfl_xor(mx, 4));
            mx = fmaxf(mx, __shfl_xor(mx, 8));
            float m_new = fmaxf(m_run[r], mx);           // stays finite (init -1e30)
            float corr = __expf(m_run[r] - m_new);
            m_run[r] = m_new;
            float rsum = 0.f;
#pragma unroll
            for (int ct = 0; ct < 4; ct++) {
                float p = __expf(s[ct][r] - m_new);      // -inf score -> 0
                s[ct][r] = p;
                rsum += p;
            }
            rsum += __shfl_xor(rsum, 1);
            rsum += __shfl_xor(rsum, 2);
            rsum += __shfl_xor(rsum, 4);
            rsum += __shfl_xor(rsum, 8);
            l_run[r] = l_run[r] * corr + rsum;
#pragma unroll
            for (int t = 0; t < 4; t++) o[t][r] *= corr;
        }
        // P -> LDS (row-major [16][64] bf16, XOR-swizzled to break bank conflicts)
#pragma unroll
        for (int ct = 0; ct < 4; ct++)
#pragma unroll
            for (int r = 0; r < 4; r++) {
                int row = lg * 4 + r;
                int idx = (row * 64 + ct * 16 + lr) ^ ((row & 7) << 3);
                P[idx] = f2bf(s[ct][r]);
            }
        // PV
#pragma unroll
        for (int t = 0; t < 4; t++) {
#pragma unroll
            for (int kk = 0; kk < 2; kk++) {
                int pidx = (lr * 64 + kk * 32 + lg * 8) ^ ((lr & 7) << 3);
                bf16x8 ap = *(const bf16x8*)(P + pidx);
                bf16x8 bv = *(const bf16x8*)(Vt + (size_t)(h * DH + t * 16 + lr) * NC + c0 + kk * 32 + lg * 8);
                o[t] = __builtin_amdgcn_mfma_f32_16x16x32_bf16(ap, bv, o[t], 0, 0, 0);
            }
        }
    }
#pragma unroll
    for (int t = 0; t < 4; t++) {
        int col = h * DH + t * 16 + lr;
#pragma unroll
        for (int r = 0; r < 4; r++) {
            int row = q0 + lg * 4 + r;
            Out[(size_t)row * DMODEL + col] = o[t][r] / l_run[r];
        }
    }
}

// ---------------- LayerNorm (one wave per row of 512) ----------------
__global__ __launch_bounds__(256) void k_ln(const float* __restrict__ Y,
        const float* __restrict__ g, const float* __restrict__ b, float* __restrict__ out)
{
    int lane = threadIdx.x & 63, wid = threadIdx.x >> 6;
    int row = blockIdx.x * 4 + wid;
    const float* y = Y + (size_t)row * DMODEL;
    int c0 = lane * 8;
    float v[8];
    *(float4*)&v[0] = *(const float4*)(y + c0);
    *(float4*)&v[4] = *(const float4*)(y + c0 + 4);
    float s = 0.f, sq = 0.f;
#pragma unroll
    for (int j = 0; j < 8; j++) { s += v[j]; sq += v[j] * v[j]; }
#pragma unroll
    for (int m = 1; m <= 32; m <<= 1) { s += __shfl_xor(s, m); sq += __shfl_xor(sq, m); }
    float mu = s * (1.f / DMODEL);
    float var = sq * (1.f / DMODEL) - mu * mu;
    float rs = rsqrtf(var + 1e-5f);
    float o[8];
#pragma unroll
    for (int j = 0; j < 8; j++) o[j] = (v[j] - mu) * rs * g[c0 + j] + b[c0 + j];
    float* op = out + (size_t)row * DMODEL + c0;
    *(float4*)(op) = *(float4*)&o[0];
    *(float4*)(op + 4) = *(float4*)&o[4];
}

extern "C" void kernel_launch(void* const* d_in, const int* in_sizes, int n_in,
                              void* d_out, int out_size, void* d_ws, size_t ws_size,
                              hipStream_t stream)
{
    const float* x      = (const float*)d_in[0];
    const float* W_proj = (const float*)d_in[1];
    const float* b_proj = (const float*)d_in[2];
    const float* W_q    = (const float*)d_in[3];
    const float* b_q    = (const float*)d_in[4];
    const float* W_k    = (const float*)d_in[5];
    const float* b_k    = (const float*)d_in[6];
    const float* W_v    = (const float*)d_in[7];
    const float* b_v    = (const float*)d_in[8];
    const float* k_buf  = (const float*)d_in[9];
    const float* v_buf  = (const float*)d_in[10];
    const float* ln_g   = (const float*)d_in[11];
    const float* ln_b   = (const float*)d_in[12];
    const int*   c_idx  = (const int*)d_in[13];
    float* out = (float*)d_out;

    char* ws = (char*)d_ws;
    size_t off = 0;
    auto alloc = [&](size_t bytes) -> void* {
        void* p = ws + off;
        off += (bytes + 255) & ~(size_t)255;
        return p;
    };
    u16* x_bf  = (u16*)alloc((size_t)NQ * DMODEL * 2);
    u16* kb_bf = (u16*)alloc((size_t)NC * DMODEL * 2);
    u16* vb_bf = (u16*)alloc((size_t)NC * DMODEL * 2);
    u16* Wp_t  = (u16*)alloc((size_t)DMODEL * DMODEL * 2);
    u16* Wq_t  = (u16*)alloc((size_t)DMODEL * DMODEL * 2);
    u16* Wk_t  = (u16*)alloc((size_t)DMODEL * DMODEL * 2);
    u16* Wv_t  = (u16*)alloc((size_t)DMODEL * DMODEL * 2);
    u16* qx    = (u16*)alloc((size_t)NQ * DMODEL * 2);
    u16* Qm    = (u16*)alloc((size_t)NQ * DMODEL * 2);
    u16* Km    = (u16*)alloc((size_t)NC * DMODEL * 2);
    u16* Vm    = (u16*)alloc((size_t)NC * DMODEL * 2);
    u16* Vtm   = (u16*)alloc((size_t)DMODEL * NC * 2);
    int*   counts = (int*)alloc(NC * 4);
    float* biasb  = (float*)alloc(NC * 4);
    float* att    = (float*)alloc((size_t)NQ * DMODEL * 4);

    hipMemsetAsync(counts, 0, NC * 4, stream);
    k_cvt_bf16<<<dim3((NQ * DMODEL / 4 + 255) / 256), dim3(256), 0, stream>>>(x, x_bf, NQ * DMODEL);
    k_cvt_bf16<<<dim3((NC * DMODEL / 4 + 255) / 256), dim3(256), 0, stream>>>(k_buf, kb_bf, NC * DMODEL);
    k_cvt_bf16<<<dim3((NC * DMODEL / 4 + 255) / 256), dim3(256), 0, stream>>>(v_buf, vb_bf, NC * DMODEL);
    k_transpose_bf16<1><<<dim3(16, 16), dim3(32, 8), 0, stream>>>(W_proj, Wp_t, DMODEL, DMODEL);
    k_transpose_bf16<1><<<dim3(16, 16), dim3(32, 8), 0, stream>>>(W_q,    Wq_t, DMODEL, DMODEL);
    k_transpose_bf16<1><<<dim3(16, 16), dim3(32, 8), 0, stream>>>(W_k,    Wk_t, DMODEL, DMODEL);
    k_transpose_bf16<1><<<dim3(16, 16), dim3(32, 8), 0, stream>>>(W_v,    Wv_t, DMODEL, DMODEL);
    k_hist<<<dim3(128), dim3(256), 0, stream>>>(c_idx, counts, NIDX);
    k_logbias<<<dim3(8), dim3(256), 0, stream>>>(counts, biasb, NC);

    k_gemm_bt<<<dim3(4, 64), dim3(256), 0, stream>>>(x_bf,  Wp_t, b_proj, qx, NQ, DMODEL, DMODEL);
    k_gemm_bt<<<dim3(4, 64), dim3(256), 0, stream>>>(qx,    Wq_t, b_q,    Qm, NQ, DMODEL, DMODEL);
    k_gemm_bt<<<dim3(4, 16), dim3(256), 0, stream>>>(kb_bf, Wk_t, b_k,    Km, NC, DMODEL, DMODEL);
    k_gemm_bt<<<dim3(4, 16), dim3(256), 0, stream>>>(vb_bf, Wv_t, b_v,    Vm, NC, DMODEL, DMODEL);
    k_transpose_bf16<0><<<dim3(16, 64), dim3(32, 8), 0, stream>>>(Vm, Vtm, NC, DMODEL);

    k_attn<<<dim3(NQ / 64, NHEAD), dim3(256), 0, stream>>>(Qm, Km, Vtm, biasb, att, 0.044194173824159216f);
    k_ln<<<dim3(NQ / 4), dim3(256), 0, stream>>>(att, ln_g, ln_b, out);
    (void)in_sizes; (void)n_in; (void)out_size; (void)ws_size;
}

// Round 2
// 242.552 us; speedup vs baseline: 1.3912x; 1.3912x over previous
//
#include <hip/hip_runtime.h>
#include <math.h>

typedef __bf16 bf16x8 __attribute__((ext_vector_type(8)));
typedef __bf16 bf16x4 __attribute__((ext_vector_type(4)));
typedef float f32x4 __attribute__((ext_vector_type(4)));
typedef unsigned short u16;

#define NQ 8192
#define DMODEL 512
#define NHEAD 8
#define DH 64
#define NC 2048
#define NIDX 100000

__device__ __forceinline__ u16 f2bf(float f) {
    unsigned u = __float_as_uint(f);
    u += 0x7fffu + ((u >> 16) & 1u);
    return (u16)(u >> 16);
}
__device__ __forceinline__ float bf2f(u16 h) {
    return __uint_as_float(((unsigned)h) << 16);
}

__device__ __forceinline__ void gld_lds16(const void* g, void* lds) {
    __builtin_amdgcn_global_load_lds(
        (const __attribute__((address_space(1))) unsigned int*)g,
        (__attribute__((address_space(3))) unsigned int*)lds,
        16, 0, 0);
}

// ---------------- elementwise f32 -> bf16 ----------------
__global__ void k_cvt_bf16(const float* __restrict__ in, u16* __restrict__ out, int n) {
    int i = (blockIdx.x * 256 + threadIdx.x) * 4;
    if (i < n) {
        float4 v = *(const float4*)(in + i);
        ushort4 o;
        o.x = f2bf(v.x); o.y = f2bf(v.y); o.z = f2bf(v.z); o.w = f2bf(v.w);
        *(ushort4*)(out + i) = o;
    }
}

// ---------------- transpose (f32 or bf16 in) -> bf16 out[c][r] = in[r][c] ----------------
template <int IN_F32>
__global__ void k_transpose_bf16(const void* __restrict__ in_, u16* __restrict__ out, int R, int C) {
    __shared__ float tile[32][33];
    int c0 = blockIdx.x * 32, r0 = blockIdx.y * 32;
    int tx = threadIdx.x, ty = threadIdx.y;  // (32,8)
#pragma unroll
    for (int i = 0; i < 4; i++) {
        int r = r0 + ty + i * 8;
        float v;
        if (IN_F32) v = ((const float*)in_)[(size_t)r * C + c0 + tx];
        else        v = bf2f(((const u16*)in_)[(size_t)r * C + c0 + tx]);
        tile[ty + i * 8][tx] = v;
    }
    __syncthreads();
#pragma unroll
    for (int i = 0; i < 4; i++) {
        out[(size_t)(c0 + ty + i * 8) * R + r0 + tx] = f2bf(tile[tx][ty + i * 8]);
    }
}

// ---------------- column permutation within 64-groups for V^T ----------------
// out[d][c64 + col'] = in[d][c64 + (col'&3)*16 + (col'>>2)]
__global__ void k_permC4(const u16* __restrict__ in, u16* __restrict__ out) {
    int i4 = (blockIdx.x * 256 + threadIdx.x) * 4;
    int colb = i4 & 63;                 // multiple of 4
    const u16* base = in + (i4 & ~63);
    int o = colb >> 2;
    ushort4 v;
    v.x = base[o];
    v.y = base[16 + o];
    v.z = base[32 + o];
    v.w = base[48 + o];
    *(ushort4*)(out + i4) = v;
}

// ---------------- histogram + log bias ----------------
__global__ void k_hist(const int* __restrict__ idx, int* __restrict__ counts, int n) {
    for (int i = blockIdx.x * blockDim.x + threadIdx.x; i < n; i += gridDim.x * blockDim.x)
        atomicAdd(&counts[idx[i]], 1);
}
__global__ void k_logbias(const int* __restrict__ counts, float* __restrict__ bias, int n) {
    int i = blockIdx.x * blockDim.x + threadIdx.x;
    if (i < n) bias[i] = logf((float)counts[i]);   // log(0)=-inf masks empty centroids
}

// ---------------- bf16 GEMM: C[M][N] = A[M][K] * Bt[N][K]^T + bias[N] ----------------
__global__ __launch_bounds__(256) void k_gemm_bt(
    const u16* __restrict__ A, const u16* __restrict__ Bt,
    const float* __restrict__ bias, u16* __restrict__ Cmat,
    int M, int N, int K)
{
    constexpr int LDP = 40;
    __shared__ __align__(16) u16 As[128 * LDP];
    __shared__ __align__(16) u16 Bs[128 * LDP];
    int tid = threadIdx.x;
    int lane = tid & 63, wid = tid >> 6;
    int wrow = (wid >> 1) * 64, wcol = (wid & 1) * 64;
    int m0 = blockIdx.y * 128, n0 = blockIdx.x * 128;
    int lr = lane & 15, lg = lane >> 4;
    f32x4 acc[4][4] = {};

    for (int k0 = 0; k0 < K; k0 += 32) {
#pragma unroll
        for (int c = 0; c < 2; c++) {
            int ch = tid + c * 256;
            int row = ch >> 2, colc = (ch & 3) * 8;
            uint4 av = *(const uint4*)(A + (size_t)(m0 + row) * K + k0 + colc);
            *(uint4*)(&As[row * LDP + colc]) = av;
            uint4 bv = *(const uint4*)(Bt + (size_t)(n0 + row) * K + k0 + colc);
            *(uint4*)(&Bs[row * LDP + colc]) = bv;
        }
        __syncthreads();
        bf16x8 af[4], bfr[4];
#pragma unroll
        for (int m = 0; m < 4; m++)
            af[m] = *(const bf16x8*)(&As[(wrow + m * 16 + lr) * LDP + lg * 8]);
#pragma unroll
        for (int n = 0; n < 4; n++)
            bfr[n] = *(const bf16x8*)(&Bs[(wcol + n * 16 + lr) * LDP + lg * 8]);
#pragma unroll
        for (int m = 0; m < 4; m++)
#pragma unroll
            for (int n = 0; n < 4; n++)
                acc[m][n] = __builtin_amdgcn_mfma_f32_16x16x32_bf16(af[m], bfr[n], acc[m][n], 0, 0, 0);
        __syncthreads();
    }
#pragma unroll
    for (int n = 0; n < 4; n++) {
        int col = n0 + wcol + n * 16 + lr;
        float bv = bias[col];
#pragma unroll
        for (int m = 0; m < 4; m++) {
            int rbase = m0 + wrow + m * 16 + lg * 4;
#pragma unroll
            for (int r = 0; r < 4; r++)
                Cmat[(size_t)(rbase + r) * N + col] = f2bf(acc[m][n][r] + bv);
        }
    }
}

// ---------------- flash attention over centroids ----------------
// grid (NQ/64, NHEAD), 4 waves; wave owns 16 q-rows of one head.
// K staged in LDS (dbuf, global_load_lds, pre-swizzled src); V prefetched in regs.
__global__ __launch_bounds__(256, 4) void k_attn(
    const u16* __restrict__ Q, const u16* __restrict__ Km, const u16* __restrict__ Vtp,
    const float* __restrict__ bias, float* __restrict__ Out, float scale)
{
    __shared__ float sbias[NC];                 // 8 KB
    __shared__ __align__(16) u16 sK[2 * 4096];  // 2 x 8 KB K staging
    __shared__ __align__(16) u16 sP[4 * 1024];  // per-wave 16x64 bf16 P (swizzled)
    int tid = threadIdx.x;
    int lane = tid & 63, wid = tid >> 6;
    int lr = lane & 15, lg = lane >> 4;
    int h = blockIdx.y;
    int q0 = blockIdx.x * 64 + wid * 16;

#pragma unroll
    for (int i = 0; i < 8; i++) sbias[tid + i * 256] = bias[tid + i * 256];
    __syncthreads();   // full drain; sbias visible

    // ---- K staging: LDS slot (row, u) <- Km[cn+row][h*64 + (u^(row&7))*8 ..+7]
    auto stageK = [&](int cn, int par) {
#pragma unroll
        for (int i = 0; i < 2; i++) {
            int row = wid * 16 + i * 8 + (lane >> 3);
            int du = (lane & 7) ^ (row & 7);
            const u16* src = Km + (size_t)(cn + row) * DMODEL + h * DH + du * 8;
            void* dst = (char*)sK + par * 8192 + wid * 2048 + i * 1024;  // +lane*16 by HW
            gld_lds16(src, dst);
        }
        __builtin_amdgcn_sched_barrier(0);
    };

    bf16x8 aq[2];
#pragma unroll
    for (int kk = 0; kk < 2; kk++)
        aq[kk] = *(const bf16x8*)(Q + (size_t)(q0 + lr) * DMODEL + h * DH + kk * 32 + lg * 8);

    stageK(0, 0);

    const u16* vgbase = Vtp + (size_t)(h * DH) * NC;
    bf16x8 vf[8];
#pragma unroll
    for (int t = 0; t < 4; t++)
#pragma unroll
        for (int kk = 0; kk < 2; kk++)
            vf[t * 2 + kk] = *(const bf16x8*)(vgbase + (size_t)(t * 16 + lr) * NC + kk * 32 + lg * 8);

    f32x4 o[4];
#pragma unroll
    for (int t = 0; t < 4; t++) o[t] = f32x4{0.f, 0.f, 0.f, 0.f};
    float m_run[4], l_part[4];
#pragma unroll
    for (int r = 0; r < 4; r++) { m_run[r] = -1e30f; l_part[r] = 0.f; }

    u16* P = sP + wid * 1024;

    for (int c0 = 0; c0 < NC; c0 += 64) {
        int par = (c0 >> 6) & 1;
        int cn = c0 + 64; if (cn >= NC) cn = 0;   // wrap: last-iter prefetch unused but valid

        asm volatile("s_waitcnt vmcnt(8)" ::: "memory");   // drain this wave's K-stage loads
        __builtin_amdgcn_s_barrier();                      // all waves' K(t) visible
        __builtin_amdgcn_sched_barrier(0);

        stageK(cn, par ^ 1);                               // async stage next chunk

        // ---- QK^T from LDS K (swizzled read)
        const u16* sKr = sK + par * 4096;
        f32x4 s[4];
#pragma unroll
        for (int ct = 0; ct < 4; ct++) {
            int row = ct * 16 + lr;
            f32x4 a = {0.f, 0.f, 0.f, 0.f};
#pragma unroll
            for (int kk = 0; kk < 2; kk++) {
                bf16x8 bk = *(const bf16x8*)(sKr + row * 64 + (((kk * 4 + lg) ^ (row & 7)) << 3));
                a = __builtin_amdgcn_mfma_f32_16x16x32_bf16(aq[kk], bk, a, 0, 0, 0);
            }
            float bc = sbias[c0 + ct * 16 + lr];
#pragma unroll
            for (int r = 0; r < 4; r++) s[ct][r] = a[r] * scale + bc;
        }

        // ---- deferred-max online softmax
        float mloc[4]; int pred = 0;
#pragma unroll
        for (int r = 0; r < 4; r++) {
            mloc[r] = fmaxf(fmaxf(s[0][r], s[1][r]), fmaxf(s[2][r], s[3][r]));
            pred |= (mloc[r] > m_run[r] + 8.f) ? 1 : 0;
        }
        if (__any(pred)) {
#pragma unroll
            for (int r = 0; r < 4; r++) {
                float mx = mloc[r];
                mx = fmaxf(mx, __shfl_xor(mx, 1));
                mx = fmaxf(mx, __shfl_xor(mx, 2));
                mx = fmaxf(mx, __shfl_xor(mx, 4));
                mx = fmaxf(mx, __shfl_xor(mx, 8));
                float m_new = fmaxf(m_run[r], mx);
                float corr = __expf(m_run[r] - m_new);
                m_run[r] = m_new;
                l_part[r] *= corr;
#pragma unroll
                for (int t = 0; t < 4; t++) o[t][r] *= corr;
            }
        }

        // ---- P = exp(s-m), lane-local l, packed b64 writes (cols' = lr*4+ct)
#pragma unroll
        for (int r = 0; r < 4; r++) {
            int row = lg * 4 + r;
            float p0 = __expf(s[0][r] - m_run[r]);
            float p1 = __expf(s[1][r] - m_run[r]);
            float p2 = __expf(s[2][r] - m_run[r]);
            float p3 = __expf(s[3][r] - m_run[r]);
            l_part[r] += (p0 + p1) + (p2 + p3);
            bf16x4 pk;
            pk[0] = (__bf16)p0; pk[1] = (__bf16)p1; pk[2] = (__bf16)p2; pk[3] = (__bf16)p3;
            int idx = row * 64 + (((lr >> 1) ^ (row & 7)) << 3) + ((lr & 1) << 2);
            *(bf16x4*)(P + idx) = pk;
        }

        // ---- PV (A-frag from swizzled P; B-frag = reg-prefetched permuted V^T)
        bf16x8 ap[2];
#pragma unroll
        for (int kk = 0; kk < 2; kk++) {
            int pidx = lr * 64 + (((kk * 4 + lg) ^ (lr & 7)) << 3);
            ap[kk] = *(const bf16x8*)(P + pidx);
        }
#pragma unroll
        for (int t = 0; t < 4; t++)
#pragma unroll
            for (int kk = 0; kk < 2; kk++)
                o[t] = __builtin_amdgcn_mfma_f32_16x16x32_bf16(ap[kk], vf[t * 2 + kk], o[t], 0, 0, 0);

        // ---- prefetch next V chunk (latency hidden by next QK+softmax)
#pragma unroll
        for (int t = 0; t < 4; t++)
#pragma unroll
            for (int kk = 0; kk < 2; kk++)
                vf[t * 2 + kk] = *(const bf16x8*)(vgbase + (size_t)(t * 16 + lr) * NC + cn + kk * 32 + lg * 8);
    }

    asm volatile("s_waitcnt vmcnt(0)" ::: "memory");   // drain trailing stage before LDS dealloc

#pragma unroll
    for (int r = 0; r < 4; r++) {
        float l = l_part[r];
        l += __shfl_xor(l, 1); l += __shfl_xor(l, 2);
        l += __shfl_xor(l, 4); l += __shfl_xor(l, 8);
        float rinv = 1.0f / l;
        int row = q0 + lg * 4 + r;
#pragma unroll
        for (int t = 0; t < 4; t++)
            Out[(size_t)row * DMODEL + h * DH + t * 16 + lr] = o[t][r] * rinv;
    }
}

// ---------------- LayerNorm (one wave per row of 512) ----------------
__global__ __launch_bounds__(256) void k_ln(const float* __restrict__ Y,
        const float* __restrict__ g, const float* __restrict__ b, float* __restrict__ out)
{
    int lane = threadIdx.x & 63, wid = threadIdx.x >> 6;
    int row = blockIdx.x * 4 + wid;
    const float* y = Y + (size_t)row * DMODEL;
    int c0 = lane * 8;
    float v[8];
    *(float4*)&v[0] = *(const float4*)(y + c0);
    *(float4*)&v[4] = *(const float4*)(y + c0 + 4);
    float s = 0.f, sq = 0.f;
#pragma unroll
    for (int j = 0; j < 8; j++) { s += v[j]; sq += v[j] * v[j]; }
#pragma unroll
    for (int m = 1; m <= 32; m <<= 1) { s += __shfl_xor(s, m); sq += __shfl_xor(sq, m); }
    float mu = s * (1.f / DMODEL);
    float var = sq * (1.f / DMODEL) - mu * mu;
    float rs = rsqrtf(var + 1e-5f);
    float o[8];
#pragma unroll
    for (int j = 0; j < 8; j++) o[j] = (v[j] - mu) * rs * g[c0 + j] + b[c0 + j];
    float* op = out + (size_t)row * DMODEL + c0;
    *(float4*)(op) = *(float4*)&o[0];
    *(float4*)(op + 4) = *(float4*)&o[4];
}

extern "C" void kernel_launch(void* const* d_in, const int* in_sizes, int n_in,
                              void* d_out, int out_size, void* d_ws, size_t ws_size,
                              hipStream_t stream)
{
    const float* x      = (const float*)d_in[0];
    const float* W_proj = (const float*)d_in[1];
    const float* b_proj = (const float*)d_in[2];
    const float* W_q    = (const float*)d_in[3];
    const float* b_q    = (const float*)d_in[4];
    const float* W_k    = (const float*)d_in[5];
    const float* b_k    = (const float*)d_in[6];
    const float* W_v    = (const float*)d_in[7];
    const float* b_v    = (const float*)d_in[8];
    const float* k_buf  = (const float*)d_in[9];
    const float* v_buf  = (const float*)d_in[10];
    const float* ln_g   = (const float*)d_in[11];
    const float* ln_b   = (const float*)d_in[12];
    const int*   c_idx  = (const int*)d_in[13];
    float* out = (float*)d_out;

    char* ws = (char*)d_ws;
    size_t off = 0;
    auto alloc = [&](size_t bytes) -> void* {
        void* p = ws + off;
        off += (bytes + 255) & ~(size_t)255;
        return p;
    };
    u16* x_bf  = (u16*)alloc((size_t)NQ * DMODEL * 2);
    u16* kb_bf = (u16*)alloc((size_t)NC * DMODEL * 2);
    u16* vb_bf = (u16*)alloc((size_t)NC * DMODEL * 2);
    u16* Wp_t  = (u16*)alloc((size_t)DMODEL * DMODEL * 2);
    u16* Wq_t  = (u16*)alloc((size_t)DMODEL * DMODEL * 2);
    u16* Wk_t  = (u16*)alloc((size_t)DMODEL * DMODEL * 2);
    u16* Wv_t  = (u16*)alloc((size_t)DMODEL * DMODEL * 2);
    u16* qx    = (u16*)alloc((size_t)NQ * DMODEL * 2);
    u16* Qm    = (u16*)alloc((size_t)NQ * DMODEL * 2);
    u16* Km    = (u16*)alloc((size_t)NC * DMODEL * 2);
    u16* Vm    = (u16*)alloc((size_t)NC * DMODEL * 2);
    u16* Vtm   = (u16*)alloc((size_t)DMODEL * NC * 2);
    u16* Vtp   = (u16*)alloc((size_t)DMODEL * NC * 2);
    int*   counts = (int*)alloc(NC * 4);
    float* biasb  = (float*)alloc(NC * 4);
    float* att    = (float*)alloc((size_t)NQ * DMODEL * 4);

    hipMemsetAsync(counts, 0, NC * 4, stream);
    k_cvt_bf16<<<dim3((NQ * DMODEL / 4 + 255) / 256), dim3(256), 0, stream>>>(x, x_bf, NQ * DMODEL);
    k_cvt_bf16<<<dim3((NC * DMODEL / 4 + 255) / 256), dim3(256), 0, stream>>>(k_buf, kb_bf, NC * DMODEL);
    k_cvt_bf16<<<dim3((NC * DMODEL / 4 + 255) / 256), dim3(256), 0, stream>>>(v_buf, vb_bf, NC * DMODEL);
    k_transpose_bf16<1><<<dim3(16, 16), dim3(32, 8), 0, stream>>>(W_proj, Wp_t, DMODEL, DMODEL);
    k_transpose_bf16<1><<<dim3(16, 16), dim3(32, 8), 0, stream>>>(W_q,    Wq_t, DMODEL, DMODEL);
    k_transpose_bf16<1><<<dim3(16, 16), dim3(32, 8), 0, stream>>>(W_k,    Wk_t, DMODEL, DMODEL);
    k_transpose_bf16<1><<<dim3(16, 16), dim3(32, 8), 0, stream>>>(W_v,    Wv_t, DMODEL, DMODEL);
    k_hist<<<dim3(128), dim3(256), 0, stream>>>(c_idx, counts, NIDX);
    k_logbias<<<dim3(8), dim3(256), 0, stream>>>(counts, biasb, NC);

    k_gemm_bt<<<dim3(4, 64), dim3(256), 0, stream>>>(x_bf,  Wp_t, b_proj, qx, NQ, DMODEL, DMODEL);
    k_gemm_bt<<<dim3(4, 64), dim3(256), 0, stream>>>(qx,    Wq_t, b_q,    Qm, NQ, DMODEL, DMODEL);
    k_gemm_bt<<<dim3(4, 16), dim3(256), 0, stream>>>(kb_bf, Wk_t, b_k,    Km, NC, DMODEL, DMODEL);
    k_gemm_bt<<<dim3(4, 16), dim3(256), 0, stream>>>(vb_bf, Wv_t, b_v,    Vm, NC, DMODEL, DMODEL);
    k_transpose_bf16<0><<<dim3(16, 64), dim3(32, 8), 0, stream>>>(Vm, Vtm, NC, DMODEL);
    k_permC4<<<dim3(DMODEL * NC / 4 / 256), dim3(256), 0, stream>>>(Vtm, Vtp);

    k_attn<<<dim3(NQ / 64, NHEAD), dim3(256), 0, stream>>>(Qm, Km, Vtp, biasb, att, 0.044194173824159216f);
    k_ln<<<dim3(NQ / 4), dim3(256), 0, stream>>>(att, ln_g, ln_b, out);
    (void)in_sizes; (void)n_in; (void)out_size; (void)ws_size;
}